// Round 7
// baseline (4468.741 us; speedup 1.0000x reference)
//
#include <hip/hip_runtime.h>
#include <math.h>

// ---------------- problem constants (fixed by the reference) ----------------
#define NN 50000
#define EE 800000
#define GG 256
constexpr float NEG_SLOPE = 0.2f;
constexpr float BN_EPS_C  = 1e-5f;

static inline int cdiv(long a, long b) { return (int)((a + b - 1) / b); }

// ---------------- small utility kernels ----------------
__global__ void k_fill(float* __restrict__ p, float v, int n) {
    int i = blockIdx.x * blockDim.x + threadIdx.x;
    if (i < n) p[i] = v;
}
__global__ void k_filli(int* __restrict__ p, int v, int n) {
    int i = blockIdx.x * blockDim.x + threadIdx.x;
    if (i < n) p[i] = v;
}

// ================= CSR build: deg -> rowptr(scan) -> slot scatter =================
__global__ void k_count(const int* __restrict__ dst, int* __restrict__ deg) {
    int e = blockIdx.x * blockDim.x + threadIdx.x;
    if (e < EE) atomicAdd(&deg[dst[e]], 1);
}

// 256-item blockwise inclusive Hillis-Steele -> exclusive out + block sums
__global__ void k_scan1(const int* __restrict__ x, int* __restrict__ excl,
                        int* __restrict__ bsum, int n) {
    __shared__ int s[256];
    int t = threadIdx.x;
    int i = blockIdx.x * 256 + t;
    int v = (i < n) ? x[i] : 0;
    s[t] = v; __syncthreads();
    #pragma unroll
    for (int off = 1; off < 256; off <<= 1) {
        int u = (t >= off) ? s[t - off] : 0;
        __syncthreads();
        s[t] += u;
        __syncthreads();
    }
    if (i < n) excl[i] = s[t] - v;
    if (t == 255) bsum[blockIdx.x] = s[255];
}
// single-block exclusive scan of block sums (nb <= 256)
__global__ void k_scan2(int* __restrict__ bsum, int* __restrict__ boff, int nb) {
    __shared__ int s[256];
    int t = threadIdx.x;
    int v = (t < nb) ? bsum[t] : 0;
    s[t] = v; __syncthreads();
    #pragma unroll
    for (int off = 1; off < 256; off <<= 1) {
        int u = (t >= off) ? s[t - off] : 0;
        __syncthreads();
        s[t] += u;
        __syncthreads();
    }
    if (t < nb) boff[t] = s[t] - v;
}
// final rowptr: excl + block offset; rowptr[NN] = EE
__global__ void k_scan3(const int* __restrict__ excl, const int* __restrict__ boff,
                        int* __restrict__ rowptr) {
    int i = blockIdx.x * blockDim.x + threadIdx.x;
    if (i < NN) rowptr[i] = excl[i] + boff[i >> 8];
    else if (i == NN) rowptr[NN] = EE;
}
// scatter edges into CSR slots; srcs_csr[pos]=src, inv[e]=pos
__global__ void k_scatter_ids(const int* __restrict__ src, const int* __restrict__ dst,
                              const int* __restrict__ rowptr, int* __restrict__ fill,
                              int* __restrict__ srcs_csr, int* __restrict__ inv) {
    int e = blockIdx.x * blockDim.x + threadIdx.x;
    if (e >= EE) return;
    int d = dst[e];
    int slot = atomicAdd(&fill[d], 1);
    int pos = rowptr[d] + slot;
    srcs_csr[pos] = src[e];
    inv[e] = pos;
}

// ================= GIN: gather-reduce, fused with self add =================
// wave per node, lane = channel; out = h[v] + sum_{in-edges} h[src]
__global__ void k_gin_gather(const float* __restrict__ h, const int* __restrict__ rowptr,
                             const int* __restrict__ srcs_csr, float* __restrict__ out) {
    int gt = blockIdx.x * blockDim.x + threadIdx.x;
    int v = gt >> 6, l = gt & 63;
    if (v >= NN) return;
    int r0 = rowptr[v], r1 = rowptr[v + 1];
    float acc = h[(long)v * 64 + l];
    for (int j = r0; j < r1; ++j) {
        int s = srcs_csr[j];
        acc += h[(long)s * 64 + l];
    }
    out[(long)v * 64 + l] = acc;
}

// ---------------- register-tiled SGEMM: out = act(bn(A @ W + bias)) ----
// A: n x K, W: K x M (row-major), out: n x M.
// Block: 256 threads, 64 rows x M cols; thread micro-tile RPT x 4.
template<int K, int M, bool BN, bool RELU>
__global__ __launch_bounds__(256)
void k_mm(const float* __restrict__ A,
          const float* __restrict__ W, const float* __restrict__ bias,
          const float* __restrict__ bng, const float* __restrict__ bnb,
          const float* __restrict__ bnm, const float* __restrict__ bnv,
          float* __restrict__ out, int n) {
    constexpr int TX  = M / 4;       // threads along cols (16 or 32)
    constexpr int TY  = 256 / TX;    // threads along rows (16 or 8)
    constexpr int RPT = 64 / TY;     // rows per thread (4 or 8)
    constexpr int KB  = 16;          // K chunk
    __shared__ float As[64][KB + 4]; // +4 pad keeps float4 alignment
    __shared__ float Ws[KB][M];
    const int tid = threadIdx.x;
    const int tx = tid % TX, ty = tid / TX;
    const int row0 = blockIdx.x * 64;

    float acc[RPT][4];
    #pragma unroll
    for (int i = 0; i < RPT; ++i)
        { acc[i][0] = 0.f; acc[i][1] = 0.f; acc[i][2] = 0.f; acc[i][3] = 0.f; }

    for (int kb = 0; kb < K; kb += KB) {
        {   // stage A chunk: 64 rows x 16 cols, one float4 per thread
            int r = tid >> 2;
            int c4 = (tid & 3) * 4;
            int row = row0 + r;
            float4 v = make_float4(0.f, 0.f, 0.f, 0.f);
            if (row < n) v = *(const float4*)&A[(long)row * K + kb + c4];
            *(float4*)&As[r][c4] = v;
        }
        #pragma unroll
        for (int i = tid; i < KB * M / 4; i += 256) {
            int k = i / (M / 4), m4 = (i % (M / 4)) * 4;
            *(float4*)&Ws[k][m4] = *(const float4*)&W[(long)(kb + k) * M + m4];
        }
        __syncthreads();
        #pragma unroll
        for (int kk4 = 0; kk4 < KB / 4; ++kk4) {
            float4 a[RPT];
            #pragma unroll
            for (int i = 0; i < RPT; ++i)
                a[i] = *(const float4*)&As[i * TY + ty][kk4 * 4];
            #pragma unroll
            for (int j = 0; j < 4; ++j) {
                float4 w = *(const float4*)&Ws[kk4 * 4 + j][tx * 4];
                #pragma unroll
                for (int i = 0; i < RPT; ++i) {
                    float av = (j == 0) ? a[i].x : (j == 1) ? a[i].y : (j == 2) ? a[i].z : a[i].w;
                    acc[i][0] += av * w.x;
                    acc[i][1] += av * w.y;
                    acc[i][2] += av * w.z;
                    acc[i][3] += av * w.w;
                }
            }
        }
        __syncthreads();
    }

    const int c0 = tx * 4;
    float4 bb = *(const float4*)&bias[c0];
    float4 sc, sh;
    if (BN) {
        float4 g = *(const float4*)&bng[c0];
        float4 b = *(const float4*)&bnb[c0];
        float4 m = *(const float4*)&bnm[c0];
        float4 vv = *(const float4*)&bnv[c0];
        sc.x = g.x * rsqrtf(vv.x + BN_EPS_C); sc.y = g.y * rsqrtf(vv.y + BN_EPS_C);
        sc.z = g.z * rsqrtf(vv.z + BN_EPS_C); sc.w = g.w * rsqrtf(vv.w + BN_EPS_C);
        sh.x = b.x - m.x * sc.x; sh.y = b.y - m.y * sc.y;
        sh.z = b.z - m.z * sc.z; sh.w = b.w - m.w * sc.w;
    }
    #pragma unroll
    for (int i = 0; i < RPT; ++i) {
        int row = row0 + i * TY + ty;
        if (row >= n) continue;
        float4 v;
        v.x = acc[i][0] + bb.x; v.y = acc[i][1] + bb.y;
        v.z = acc[i][2] + bb.z; v.w = acc[i][3] + bb.w;
        if (BN) {
            v.x = v.x * sc.x + sh.x; v.y = v.y * sc.y + sh.y;
            v.z = v.z * sc.z + sh.z; v.w = v.w * sc.w + sh.w;
        }
        if (RELU) {
            v.x = fmaxf(v.x, 0.f); v.y = fmaxf(v.y, 0.f);
            v.z = fmaxf(v.z, 0.f); v.w = fmaxf(v.w, 0.f);
        }
        *(float4*)&out[(long)row * M + c0] = v;
    }
}

// ================= GATv2 pass A: per-edge alpha, stored at CSR position =================
// wave per real edge; self-loop alphas computed inline in pass B.
template<int HH, int M>
__global__ void k_gat_alpha(const float* __restrict__ xl, const float* __restrict__ xr,
                            const float* __restrict__ att, const int* __restrict__ src,
                            const int* __restrict__ dst, const int* __restrict__ inv,
                            float* __restrict__ alpha_csr) {
    int gt = blockIdx.x * blockDim.x + threadIdx.x;
    int e = gt >> 6, lane = gt & 63;
    if (e >= EE) return;
    int s = src[e], d = dst[e];
    int pos = inv[e];
    #pragma unroll
    for (int h = 0; h < HH; ++h) {
        float v = xl[(long)s * M + h * 64 + lane] + xr[(long)d * M + h * 64 + lane];
        v = (v > 0.0f) ? v : NEG_SLOPE * v;
        float p = v * att[h * 64 + lane];
        #pragma unroll
        for (int off = 32; off; off >>= 1) p += __shfl_xor(p, off);
        if (lane == 0) alpha_csr[(long)pos * HH + h] = p;
    }
}

// ================= GATv2 pass B: node-gather online softmax + accumulate + bias + relu ====
// block = HH waves per node; wave h handles head h; lane = channel.
template<int HH, int M>
__global__ void k_gat_gather(const float* __restrict__ xl, const float* __restrict__ xr,
                             const float* __restrict__ att, const int* __restrict__ rowptr,
                             const int* __restrict__ srcs_csr, const float* __restrict__ alpha_csr,
                             const float* __restrict__ bias, float* __restrict__ out) {
    int v = blockIdx.x;
    int h = threadIdx.x >> 6, l = threadIdx.x & 63;
    int c = h * 64 + l;
    float xl_v = xl[(long)v * M + c];
    float xr_v = xr[(long)v * M + c];
    // self-loop alpha
    float t = xl_v + xr_v;
    t = (t > 0.0f) ? t : NEG_SLOPE * t;
    float p = t * att[c];
    #pragma unroll
    for (int off = 32; off; off >>= 1) p += __shfl_xor(p, off);
    float a_self = p;                       // identical on all lanes of the wave
    int r0 = rowptr[v], r1 = rowptr[v + 1];
    // online softmax max/denom over {self} U in-edges
    float m = a_self, den = 1.0f;
    for (int j = r0; j < r1; ++j) {
        float a = alpha_csr[(long)j * HH + h];
        if (a > m) { den = den * __expf(m - a) + 1.0f; m = a; }
        else       { den += __expf(a - m); }
    }
    // weighted accumulate
    float acc = __expf(a_self - m) * xl_v;
    for (int j = r0; j < r1; ++j) {
        float a = alpha_csr[(long)j * HH + h];
        int s = srcs_csr[j];
        acc += __expf(a - m) * xl[(long)s * M + c];
    }
    float o = acc / (den + 1e-16f) + bias[c];
    out[(long)v * M + c] = fmaxf(o, 0.0f);
}

// ---------------- mean pool (atomics) ----------------
__global__ void k_pool(const float* __restrict__ gin, const float* __restrict__ gat,
                       const int* __restrict__ batch, float* __restrict__ pooled,
                       float* __restrict__ counts) {
    int i = blockIdx.x * blockDim.x + threadIdx.x;
    if (i >= NN * 128) return;
    int v = i >> 7, c = i & 127;
    int g = batch[v];
    float val = (c < 64) ? gin[v * 64 + c] : gat[v * 64 + (c - 64)];
    atomicAdd(&pooled[g * 128 + c], val);
    if (c == 0) atomicAdd(&counts[g], 1.0f);
}

// ---------------- graph head ----------------
__global__ void k_head(const float* __restrict__ pooled, const float* __restrict__ counts,
                       const float* __restrict__ gw, const float* __restrict__ gb,
                       const float* __restrict__ cw, const float* __restrict__ cb,
                       float* __restrict__ out) {
    int g = blockIdx.x;
    int j = threadIdx.x;      // 64 threads = 1 wave
    __shared__ float prow[128];
    float cnt = fmaxf(counts[g], 1.0f);
    prow[j]      = pooled[g * 128 + j] / cnt;
    prow[j + 64] = pooled[g * 128 + 64 + j] / cnt;
    __syncthreads();
    float acc = gb[j];
    #pragma unroll
    for (int k = 0; k < 128; ++k) acc += prow[k] * gw[k * 64 + j];
    out[GG + g * 65 + j] = acc;
    if (j == 0) out[GG + g * 65 + 64] = 0.0f;     // lovasz stub
    float p = acc * cw[j];
    #pragma unroll
    for (int off = 32; off; off >>= 1) p += __shfl_xor(p, off);
    if (j == 0) out[g] = p + cb[0];
}

// ---------------- host launcher ----------------
extern "C" void kernel_launch(void* const* d_in, const int* in_sizes, int n_in,
                              void* d_out, int out_size, void* d_ws, size_t ws_size,
                              hipStream_t stream) {
    const float* x        = (const float*)d_in[0];
    const int*   ei       = (const int*)d_in[1];
    const int*   src      = ei;
    const int*   dst      = ei + EE;
    const int*   batch    = (const int*)d_in[2];
    const float* gin_w1   = (const float*)d_in[3];
    const float* gin_b1   = (const float*)d_in[4];
    const float* gin_bn_g = (const float*)d_in[5];
    const float* gin_bn_b = (const float*)d_in[6];
    const float* gin_bn_m = (const float*)d_in[7];
    const float* gin_bn_v = (const float*)d_in[8];
    const float* gin_w2   = (const float*)d_in[9];
    const float* gin_b2   = (const float*)d_in[10];
    const float* gat_wl[3]   = {(const float*)d_in[11], (const float*)d_in[17], (const float*)d_in[23]};
    const float* gat_bl[3]   = {(const float*)d_in[12], (const float*)d_in[18], (const float*)d_in[24]};
    const float* gat_wr[3]   = {(const float*)d_in[13], (const float*)d_in[19], (const float*)d_in[25]};
    const float* gat_br[3]   = {(const float*)d_in[14], (const float*)d_in[20], (const float*)d_in[26]};
    const float* gat_att[3]  = {(const float*)d_in[15], (const float*)d_in[21], (const float*)d_in[27]};
    const float* gat_bias[3] = {(const float*)d_in[16], (const float*)d_in[22], (const float*)d_in[28]};
    const float* graph_w  = (const float*)d_in[29];
    const float* graph_b  = (const float*)d_in[30];
    const float* clf_w    = (const float*)d_in[31];
    const float* clf_b    = (const float*)d_in[32];
    float* out = (float*)d_out;

    // ---- workspace carve-up (16B-aligned chunks) ----
    float* ws = (float*)d_ws;
    size_t o = 0;
    auto alloc = [&](size_t n) { float* p = ws + o; o += (n + 3) & ~(size_t)3; return p; };
    float* gin_h    = alloc((size_t)NN * 64);
    float* gin_hsum = alloc((size_t)NN * 64);
    float* gin_tmp  = alloc((size_t)NN * 64);
    float* gat_h    = alloc((size_t)NN * 128);
    float* gat_xl   = alloc((size_t)NN * 128);
    float* gat_xr   = alloc((size_t)NN * 128);
    float* gat_out  = alloc((size_t)NN * 64);
    float* alpha    = alloc((size_t)EE * 2);      // alpha in CSR order
    float* pooled   = alloc((size_t)GG * 128);
    float* counts   = alloc((size_t)GG);
    int* deg      = (int*)alloc((size_t)NN);
    int* fillc    = (int*)alloc((size_t)NN);
    int* excl     = (int*)alloc((size_t)NN);
    int* rowptr   = (int*)alloc((size_t)NN + 1);
    int* bsum     = (int*)alloc(256);
    int* boff     = (int*)alloc(256);
    int* srcs_csr = (int*)alloc((size_t)EE);
    int* inv      = (int*)alloc((size_t)EE);
    (void)ws_size; (void)n_in; (void)in_sizes; (void)out_size;

    const int TB = 256;
    const int NB_SCAN = cdiv(NN, 256);   // 196

    // =================== CSR build (shared by GIN + GAT) ===================
    k_filli<<<cdiv(NN, TB), TB, 0, stream>>>(deg, 0, NN);
    k_filli<<<cdiv(NN, TB), TB, 0, stream>>>(fillc, 0, NN);
    k_count<<<cdiv(EE, TB), TB, 0, stream>>>(dst, deg);
    k_scan1<<<NB_SCAN, 256, 0, stream>>>(deg, excl, bsum, NN);
    k_scan2<<<1, 256, 0, stream>>>(bsum, boff, NB_SCAN);
    k_scan3<<<cdiv(NN + 1, TB), TB, 0, stream>>>(excl, boff, rowptr);
    k_scatter_ids<<<cdiv(EE, TB), TB, 0, stream>>>(src, dst, rowptr, fillc, srcs_csr, inv);

    // =================== GIN encoder ===================
    const float* hin = x;
    for (int l = 0; l < 3; ++l) {
        k_gin_gather<<<cdiv((long)NN * 64, TB), TB, 0, stream>>>(hin, rowptr, srcs_csr, gin_hsum);
        k_mm<64, 64, true, true><<<cdiv(NN, 64), 256, 0, stream>>>(
            gin_hsum, gin_w1 + l * 4096, gin_b1 + l * 64,
            gin_bn_g + l * 64, gin_bn_b + l * 64, gin_bn_m + l * 64, gin_bn_v + l * 64,
            gin_tmp, NN);
        k_mm<64, 64, false, true><<<cdiv(NN, 64), 256, 0, stream>>>(
            gin_tmp, gin_w2 + l * 4096, gin_b2 + l * 64,
            nullptr, nullptr, nullptr, nullptr, gin_h, NN);
        hin = gin_h;
    }

    // =================== GATv2 encoder ===================
    const float* hg = x;
    for (int l = 0; l < 3; ++l) {
        if (l == 0) {
            k_mm<64, 128, false, false><<<cdiv(NN, 64), 256, 0, stream>>>(
                hg, gat_wl[l], gat_bl[l], nullptr, nullptr, nullptr, nullptr, gat_xl, NN);
            k_mm<64, 128, false, false><<<cdiv(NN, 64), 256, 0, stream>>>(
                hg, gat_wr[l], gat_br[l], nullptr, nullptr, nullptr, nullptr, gat_xr, NN);
            k_gat_alpha<2, 128><<<cdiv((long)EE * 64, TB), TB, 0, stream>>>(
                gat_xl, gat_xr, gat_att[l], src, dst, inv, alpha);
            k_gat_gather<2, 128><<<NN, 128, 0, stream>>>(
                gat_xl, gat_xr, gat_att[l], rowptr, srcs_csr, alpha, gat_bias[l], gat_h);
            hg = gat_h;
        } else if (l == 1) {
            k_mm<128, 128, false, false><<<cdiv(NN, 64), 256, 0, stream>>>(
                hg, gat_wl[l], gat_bl[l], nullptr, nullptr, nullptr, nullptr, gat_xl, NN);
            k_mm<128, 128, false, false><<<cdiv(NN, 64), 256, 0, stream>>>(
                hg, gat_wr[l], gat_br[l], nullptr, nullptr, nullptr, nullptr, gat_xr, NN);
            k_gat_alpha<2, 128><<<cdiv((long)EE * 64, TB), TB, 0, stream>>>(
                gat_xl, gat_xr, gat_att[l], src, dst, inv, alpha);
            k_gat_gather<2, 128><<<NN, 128, 0, stream>>>(
                gat_xl, gat_xr, gat_att[l], rowptr, srcs_csr, alpha, gat_bias[l], gat_h);
            hg = gat_h;
        } else {
            k_mm<128, 64, false, false><<<cdiv(NN, 64), 256, 0, stream>>>(
                hg, gat_wl[l], gat_bl[l], nullptr, nullptr, nullptr, nullptr, gat_xl, NN);
            k_mm<128, 64, false, false><<<cdiv(NN, 64), 256, 0, stream>>>(
                hg, gat_wr[l], gat_br[l], nullptr, nullptr, nullptr, nullptr, gat_xr, NN);
            k_gat_alpha<1, 64><<<cdiv((long)EE * 64, TB), TB, 0, stream>>>(
                gat_xl, gat_xr, gat_att[l], src, dst, inv, alpha);
            k_gat_gather<1, 64><<<NN, 64, 0, stream>>>(
                gat_xl, gat_xr, gat_att[l], rowptr, srcs_csr, alpha, gat_bias[l], gat_out);
        }
    }

    // =================== pool + heads ===================
    k_fill<<<cdiv((long)GG * 129, TB), TB, 0, stream>>>(pooled, 0.0f, GG * 129); // pooled+counts contiguous
    k_pool<<<cdiv((long)NN * 128, TB), TB, 0, stream>>>(gin_h, gat_out, batch, pooled, counts);
    k_head<<<GG, 64, 0, stream>>>(pooled, counts, graph_w, graph_b, clf_w, clf_b, out);
}

// Round 12
// 1471.536 us; speedup vs baseline: 3.0368x; 3.0368x over previous
//
#include <hip/hip_runtime.h>
#include <math.h>

// ---------------- problem constants (fixed by the reference) ----------------
#define NN 50000
#define EE 800000
#define GG 256
constexpr float NEG_SLOPE = 0.2f;
constexpr float BN_EPS_C  = 1e-5f;

static inline int cdiv(long a, long b) { return (int)((a + b - 1) / b); }

// ---------------- small utility kernels ----------------
__global__ void k_fill(float* __restrict__ p, float v, int n) {
    int i = blockIdx.x * blockDim.x + threadIdx.x;
    if (i < n) p[i] = v;
}
__global__ void k_filli(int* __restrict__ p, int v, int n) {
    int i = blockIdx.x * blockDim.x + threadIdx.x;
    if (i < n) p[i] = v;
}

// ================= CSR build: deg -> rowptr(scan) -> slot scatter =================
__global__ void k_count(const int* __restrict__ dst, int* __restrict__ deg) {
    int e = blockIdx.x * blockDim.x + threadIdx.x;
    if (e < EE) atomicAdd(&deg[dst[e]], 1);
}

// 256-item blockwise inclusive Hillis-Steele -> exclusive out + block sums
__global__ void k_scan1(const int* __restrict__ x, int* __restrict__ excl,
                        int* __restrict__ bsum, int n) {
    __shared__ int s[256];
    int t = threadIdx.x;
    int i = blockIdx.x * 256 + t;
    int v = (i < n) ? x[i] : 0;
    s[t] = v; __syncthreads();
    #pragma unroll
    for (int off = 1; off < 256; off <<= 1) {
        int u = (t >= off) ? s[t - off] : 0;
        __syncthreads();
        s[t] += u;
        __syncthreads();
    }
    if (i < n) excl[i] = s[t] - v;
    if (t == 255) bsum[blockIdx.x] = s[255];
}
// single-block exclusive scan of block sums (nb <= 256)
__global__ void k_scan2(int* __restrict__ bsum, int* __restrict__ boff, int nb) {
    __shared__ int s[256];
    int t = threadIdx.x;
    int v = (t < nb) ? bsum[t] : 0;
    s[t] = v; __syncthreads();
    #pragma unroll
    for (int off = 1; off < 256; off <<= 1) {
        int u = (t >= off) ? s[t - off] : 0;
        __syncthreads();
        s[t] += u;
        __syncthreads();
    }
    if (t < nb) boff[t] = s[t] - v;
}
// final rowptr: excl + block offset; rowptr[NN] = EE
__global__ void k_scan3(const int* __restrict__ excl, const int* __restrict__ boff,
                        int* __restrict__ rowptr) {
    int i = blockIdx.x * blockDim.x + threadIdx.x;
    if (i < NN) rowptr[i] = excl[i] + boff[i >> 8];
    else if (i == NN) rowptr[NN] = EE;
}
// scatter edges into CSR slots
__global__ void k_scatter_ids(const int* __restrict__ src, const int* __restrict__ dst,
                              const int* __restrict__ rowptr, int* __restrict__ fill,
                              int* __restrict__ srcs_csr) {
    int e = blockIdx.x * blockDim.x + threadIdx.x;
    if (e >= EE) return;
    int d = dst[e];
    int slot = atomicAdd(&fill[d], 1);
    srcs_csr[rowptr[d] + slot] = src[e];
}

// ================= GIN: gather-reduce, fused with self add =================
// wave per node, lane = channel; out = h[v] + sum_{in-edges} h[src]
__global__ void k_gin_gather(const float* __restrict__ h, const int* __restrict__ rowptr,
                             const int* __restrict__ srcs_csr, float* __restrict__ out) {
    int gt = blockIdx.x * blockDim.x + threadIdx.x;
    int v = gt >> 6, l = gt & 63;
    if (v >= NN) return;
    int r0 = rowptr[v], r1 = rowptr[v + 1];
    float acc = h[(long)v * 64 + l];
    for (int j = r0; j < r1; ++j) {
        int s = srcs_csr[j];
        acc += h[(long)s * 64 + l];
    }
    out[(long)v * 64 + l] = acc;
}

// ---------------- register-tiled SGEMM: out = act(bn(A @ W + bias)) ----
// A: n x K, W: K x M (row-major), out: n x M.
// Block: 256 threads -> 64 rows x 64 cols (blockIdx.y = 64-col tile of M).
// Thread micro-tile 4x4 -> acc[4][4]: low register pressure by design
// (R7 post-mortem: 64x128 tile spilled at 256 VGPRs, 1.8 GB scratch traffic).
template<int K, int M, bool BN, bool RELU>
__global__ __launch_bounds__(256)
void k_mm(const float* __restrict__ A,
          const float* __restrict__ W, const float* __restrict__ bias,
          const float* __restrict__ bng, const float* __restrict__ bnb,
          const float* __restrict__ bnm, const float* __restrict__ bnv,
          float* __restrict__ out, int n) {
    constexpr int KB = 16;           // K chunk
    __shared__ float As[64][KB + 4]; // +4 pad: float4-aligned rows, bank spread
    __shared__ float Ws[KB][64];
    const int tid  = threadIdx.x;
    const int tx   = tid & 15;       // 16 col-groups of 4
    const int ty   = tid >> 4;       // 16 row-groups of 4
    const int row0 = blockIdx.x * 64;
    const int col0 = blockIdx.y * 64;

    float acc[4][4];
    #pragma unroll
    for (int i = 0; i < 4; ++i)
        { acc[i][0] = 0.f; acc[i][1] = 0.f; acc[i][2] = 0.f; acc[i][3] = 0.f; }

    for (int kb = 0; kb < K; kb += KB) {
        {   // stage A chunk: 64 rows x 16 cols, one float4 per thread
            int r = tid >> 2, c4 = (tid & 3) * 4;
            int row = row0 + r;
            float4 v = make_float4(0.f, 0.f, 0.f, 0.f);
            if (row < n) v = *(const float4*)&A[(long)row * K + kb + c4];
            *(float4*)&As[r][c4] = v;
        }
        {   // stage W chunk: 16 x 64 slice, one float4 per thread
            int wk = tid >> 4, wm4 = (tid & 15) * 4;
            *(float4*)&Ws[wk][wm4] = *(const float4*)&W[(long)(kb + wk) * M + col0 + wm4];
        }
        __syncthreads();
        #pragma unroll
        for (int kk = 0; kk < KB; ++kk) {
            float4 w = *(const float4*)&Ws[kk][tx * 4];
            #pragma unroll
            for (int i = 0; i < 4; ++i) {
                float av = As[i * 16 + ty][kk];
                acc[i][0] += av * w.x;
                acc[i][1] += av * w.y;
                acc[i][2] += av * w.z;
                acc[i][3] += av * w.w;
            }
        }
        __syncthreads();
    }

    const int c0 = col0 + tx * 4;
    float4 bb = *(const float4*)&bias[c0];
    float4 sc, sh;
    if (BN) {
        float4 g = *(const float4*)&bng[c0];
        float4 b = *(const float4*)&bnb[c0];
        float4 m = *(const float4*)&bnm[c0];
        float4 vv = *(const float4*)&bnv[c0];
        sc.x = g.x * rsqrtf(vv.x + BN_EPS_C); sc.y = g.y * rsqrtf(vv.y + BN_EPS_C);
        sc.z = g.z * rsqrtf(vv.z + BN_EPS_C); sc.w = g.w * rsqrtf(vv.w + BN_EPS_C);
        sh.x = b.x - m.x * sc.x; sh.y = b.y - m.y * sc.y;
        sh.z = b.z - m.z * sc.z; sh.w = b.w - m.w * sc.w;
    }
    #pragma unroll
    for (int i = 0; i < 4; ++i) {
        int row = row0 + i * 16 + ty;
        if (row >= n) continue;
        float4 v;
        v.x = acc[i][0] + bb.x; v.y = acc[i][1] + bb.y;
        v.z = acc[i][2] + bb.z; v.w = acc[i][3] + bb.w;
        if (BN) {
            v.x = v.x * sc.x + sh.x; v.y = v.y * sc.y + sh.y;
            v.z = v.z * sc.z + sh.z; v.w = v.w * sc.w + sh.w;
        }
        if (RELU) {
            v.x = fmaxf(v.x, 0.f); v.y = fmaxf(v.y, 0.f);
            v.z = fmaxf(v.z, 0.f); v.w = fmaxf(v.w, 0.f);
        }
        *(float4*)&out[(long)row * M + c0] = v;
    }
}

// ================= GATv2 fused: alpha + online softmax + accumulate + bias + relu ======
// One block per node; wave h = head h; lane = channel within head.
// Alpha recomputed in the accumulate pass (bitwise-identical; xl row is cache-hot).
// Eliminates the 51M-thread edge kernel + alpha/inv buffers (R7 top offender).
template<int HH, int M>
__global__ void k_gat_fused(const float* __restrict__ xl, const float* __restrict__ xr,
                            const float* __restrict__ att, const int* __restrict__ rowptr,
                            const int* __restrict__ srcs_csr,
                            const float* __restrict__ bias, float* __restrict__ out) {
    int v = blockIdx.x;
    int h = threadIdx.x >> 6, l = threadIdx.x & 63;
    int c = h * 64 + l;
    float attc = att[c];
    float xl_v = xl[(long)v * M + c];
    float xr_v = xr[(long)v * M + c];
    // self-loop alpha
    float t = xl_v + xr_v;
    t = (t > 0.0f) ? t : NEG_SLOPE * t;
    float p = t * attc;
    #pragma unroll
    for (int off = 32; off; off >>= 1) p += __shfl_xor(p, off);
    const float a_self = p;                  // identical on all lanes of the wave
    const int r0 = rowptr[v], r1 = rowptr[v + 1];
    // pass 1: online softmax max/denom over {self} U in-edges
    float m = a_self, den = 1.0f;
    for (int j = r0; j < r1; ++j) {
        int s = srcs_csr[j];
        float xs = xl[(long)s * M + c];
        float tt = xs + xr_v;
        tt = (tt > 0.0f) ? tt : NEG_SLOPE * tt;
        float a = tt * attc;
        #pragma unroll
        for (int off = 32; off; off >>= 1) a += __shfl_xor(a, off);
        if (a > m) { den = den * __expf(m - a) + 1.0f; m = a; }  // uniform branch
        else       { den += __expf(a - m); }
    }
    // pass 2: weighted accumulate (alpha recomputed, reads are L1/L2-hot)
    float acc = __expf(a_self - m) * xl_v;
    for (int j = r0; j < r1; ++j) {
        int s = srcs_csr[j];
        float xs = xl[(long)s * M + c];
        float tt = xs + xr_v;
        tt = (tt > 0.0f) ? tt : NEG_SLOPE * tt;
        float a = tt * attc;
        #pragma unroll
        for (int off = 32; off; off >>= 1) a += __shfl_xor(a, off);
        acc += __expf(a - m) * xs;
    }
    float o = acc / (den + 1e-16f) + bias[c];
    out[(long)v * M + c] = fmaxf(o, 0.0f);
}

// ---------------- mean pool (atomics) ----------------
__global__ void k_pool(const float* __restrict__ gin, const float* __restrict__ gat,
                       const int* __restrict__ batch, float* __restrict__ pooled,
                       float* __restrict__ counts) {
    int i = blockIdx.x * blockDim.x + threadIdx.x;
    if (i >= NN * 128) return;
    int v = i >> 7, c = i & 127;
    int g = batch[v];
    float val = (c < 64) ? gin[v * 64 + c] : gat[v * 64 + (c - 64)];
    atomicAdd(&pooled[g * 128 + c], val);
    if (c == 0) atomicAdd(&counts[g], 1.0f);
}

// ---------------- graph head ----------------
__global__ void k_head(const float* __restrict__ pooled, const float* __restrict__ counts,
                       const float* __restrict__ gw, const float* __restrict__ gb,
                       const float* __restrict__ cw, const float* __restrict__ cb,
                       float* __restrict__ out) {
    int g = blockIdx.x;
    int j = threadIdx.x;      // 64 threads = 1 wave
    __shared__ float prow[128];
    float cnt = fmaxf(counts[g], 1.0f);
    prow[j]      = pooled[g * 128 + j] / cnt;
    prow[j + 64] = pooled[g * 128 + 64 + j] / cnt;
    __syncthreads();
    float acc = gb[j];
    #pragma unroll
    for (int k = 0; k < 128; ++k) acc += prow[k] * gw[k * 64 + j];
    out[GG + g * 65 + j] = acc;
    if (j == 0) out[GG + g * 65 + 64] = 0.0f;     // lovasz stub
    float p = acc * cw[j];
    #pragma unroll
    for (int off = 32; off; off >>= 1) p += __shfl_xor(p, off);
    if (j == 0) out[g] = p + cb[0];
}

// ---------------- host launcher ----------------
extern "C" void kernel_launch(void* const* d_in, const int* in_sizes, int n_in,
                              void* d_out, int out_size, void* d_ws, size_t ws_size,
                              hipStream_t stream) {
    const float* x        = (const float*)d_in[0];
    const int*   ei       = (const int*)d_in[1];
    const int*   src      = ei;
    const int*   dst      = ei + EE;
    const int*   batch    = (const int*)d_in[2];
    const float* gin_w1   = (const float*)d_in[3];
    const float* gin_b1   = (const float*)d_in[4];
    const float* gin_bn_g = (const float*)d_in[5];
    const float* gin_bn_b = (const float*)d_in[6];
    const float* gin_bn_m = (const float*)d_in[7];
    const float* gin_bn_v = (const float*)d_in[8];
    const float* gin_w2   = (const float*)d_in[9];
    const float* gin_b2   = (const float*)d_in[10];
    const float* gat_wl[3]   = {(const float*)d_in[11], (const float*)d_in[17], (const float*)d_in[23]};
    const float* gat_bl[3]   = {(const float*)d_in[12], (const float*)d_in[18], (const float*)d_in[24]};
    const float* gat_wr[3]   = {(const float*)d_in[13], (const float*)d_in[19], (const float*)d_in[25]};
    const float* gat_br[3]   = {(const float*)d_in[14], (const float*)d_in[20], (const float*)d_in[26]};
    const float* gat_att[3]  = {(const float*)d_in[15], (const float*)d_in[21], (const float*)d_in[27]};
    const float* gat_bias[3] = {(const float*)d_in[16], (const float*)d_in[22], (const float*)d_in[28]};
    const float* graph_w  = (const float*)d_in[29];
    const float* graph_b  = (const float*)d_in[30];
    const float* clf_w    = (const float*)d_in[31];
    const float* clf_b    = (const float*)d_in[32];
    float* out = (float*)d_out;

    // ---- workspace carve-up (16B-aligned chunks) ----
    float* ws = (float*)d_ws;
    size_t o = 0;
    auto alloc = [&](size_t n) { float* p = ws + o; o += (n + 3) & ~(size_t)3; return p; };
    float* gin_h    = alloc((size_t)NN * 64);
    float* gin_hsum = alloc((size_t)NN * 64);
    float* gin_tmp  = alloc((size_t)NN * 64);
    float* gat_h    = alloc((size_t)NN * 128);
    float* gat_xl   = alloc((size_t)NN * 128);
    float* gat_xr   = alloc((size_t)NN * 128);
    float* gat_out  = alloc((size_t)NN * 64);
    float* pooled   = alloc((size_t)GG * 128);
    float* counts   = alloc((size_t)GG);
    int* deg      = (int*)alloc((size_t)NN);
    int* fillc    = (int*)alloc((size_t)NN);
    int* excl     = (int*)alloc((size_t)NN);
    int* rowptr   = (int*)alloc((size_t)NN + 1);
    int* bsum     = (int*)alloc(256);
    int* boff     = (int*)alloc(256);
    int* srcs_csr = (int*)alloc((size_t)EE);
    (void)ws_size; (void)n_in; (void)in_sizes; (void)out_size;

    const int TB = 256;
    const int NB_SCAN = cdiv(NN, 256);   // 196

    // =================== CSR build (shared by GIN + GAT) ===================
    k_filli<<<cdiv(NN, TB), TB, 0, stream>>>(deg, 0, NN);
    k_filli<<<cdiv(NN, TB), TB, 0, stream>>>(fillc, 0, NN);
    k_count<<<cdiv(EE, TB), TB, 0, stream>>>(dst, deg);
    k_scan1<<<NB_SCAN, 256, 0, stream>>>(deg, excl, bsum, NN);
    k_scan2<<<1, 256, 0, stream>>>(bsum, boff, NB_SCAN);
    k_scan3<<<cdiv(NN + 1, TB), TB, 0, stream>>>(excl, boff, rowptr);
    k_scatter_ids<<<cdiv(EE, TB), TB, 0, stream>>>(src, dst, rowptr, fillc, srcs_csr);

    const int NR = cdiv(NN, 64);         // 782 row-blocks

    // =================== GIN encoder ===================
    const float* hin = x;
    for (int l = 0; l < 3; ++l) {
        k_gin_gather<<<cdiv((long)NN * 64, TB), TB, 0, stream>>>(hin, rowptr, srcs_csr, gin_hsum);
        k_mm<64, 64, true, true><<<dim3(NR, 1), 256, 0, stream>>>(
            gin_hsum, gin_w1 + l * 4096, gin_b1 + l * 64,
            gin_bn_g + l * 64, gin_bn_b + l * 64, gin_bn_m + l * 64, gin_bn_v + l * 64,
            gin_tmp, NN);
        k_mm<64, 64, false, true><<<dim3(NR, 1), 256, 0, stream>>>(
            gin_tmp, gin_w2 + l * 4096, gin_b2 + l * 64,
            nullptr, nullptr, nullptr, nullptr, gin_h, NN);
        hin = gin_h;
    }

    // =================== GATv2 encoder ===================
    const float* hg = x;
    for (int l = 0; l < 3; ++l) {
        if (l == 0) {
            k_mm<64, 128, false, false><<<dim3(NR, 2), 256, 0, stream>>>(
                hg, gat_wl[l], gat_bl[l], nullptr, nullptr, nullptr, nullptr, gat_xl, NN);
            k_mm<64, 128, false, false><<<dim3(NR, 2), 256, 0, stream>>>(
                hg, gat_wr[l], gat_br[l], nullptr, nullptr, nullptr, nullptr, gat_xr, NN);
            k_gat_fused<2, 128><<<NN, 128, 0, stream>>>(
                gat_xl, gat_xr, gat_att[l], rowptr, srcs_csr, gat_bias[l], gat_h);
            hg = gat_h;
        } else if (l == 1) {
            k_mm<128, 128, false, false><<<dim3(NR, 2), 256, 0, stream>>>(
                hg, gat_wl[l], gat_bl[l], nullptr, nullptr, nullptr, nullptr, gat_xl, NN);
            k_mm<128, 128, false, false><<<dim3(NR, 2), 256, 0, stream>>>(
                hg, gat_wr[l], gat_br[l], nullptr, nullptr, nullptr, nullptr, gat_xr, NN);
            k_gat_fused<2, 128><<<NN, 128, 0, stream>>>(
                gat_xl, gat_xr, gat_att[l], rowptr, srcs_csr, gat_bias[l], gat_h);
            hg = gat_h;
        } else {
            k_mm<128, 64, false, false><<<dim3(NR, 1), 256, 0, stream>>>(
                hg, gat_wl[l], gat_bl[l], nullptr, nullptr, nullptr, nullptr, gat_xl, NN);
            k_mm<128, 64, false, false><<<dim3(NR, 1), 256, 0, stream>>>(
                hg, gat_wr[l], gat_br[l], nullptr, nullptr, nullptr, nullptr, gat_xr, NN);
            k_gat_fused<1, 64><<<NN, 64, 0, stream>>>(
                gat_xl, gat_xr, gat_att[l], rowptr, srcs_csr, gat_bias[l], gat_out);
        }
    }

    // =================== pool + heads ===================
    k_fill<<<cdiv((long)GG * 129, TB), TB, 0, stream>>>(pooled, 0.0f, GG * 129); // pooled+counts contiguous
    k_pool<<<cdiv((long)NN * 128, TB), TB, 0, stream>>>(gin_h, gat_out, batch, pooled, counts);
    k_head<<<GG, 64, 0, stream>>>(pooled, counts, graph_w, graph_b, clf_w, clf_b, out);
}

// Round 15
// 867.473 us; speedup vs baseline: 5.1514x; 1.6963x over previous
//
#include <hip/hip_runtime.h>
#include <math.h>

// ---------------- problem constants (fixed by the reference) ----------------
#define NN 50000
#define EE 800000
#define GG 256
constexpr float NEG_SLOPE = 0.2f;
constexpr float BN_EPS_C  = 1e-5f;

static inline int cdiv(long a, long b) { return (int)((a + b - 1) / b); }

// ---------------- small utility kernels ----------------
__global__ void k_fill(float* __restrict__ p, float v, int n) {
    int i = blockIdx.x * blockDim.x + threadIdx.x;
    if (i < n) p[i] = v;
}
__global__ void k_filli(int* __restrict__ p, int v, int n) {
    int i = blockIdx.x * blockDim.x + threadIdx.x;
    if (i < n) p[i] = v;
}

// ================= CSR build: deg -> rowptr(scan) -> slot scatter =================
__global__ void k_count(const int* __restrict__ dst, int* __restrict__ deg) {
    int e = blockIdx.x * blockDim.x + threadIdx.x;
    if (e < EE) atomicAdd(&deg[dst[e]], 1);
}

__global__ void k_scan1(const int* __restrict__ x, int* __restrict__ excl,
                        int* __restrict__ bsum, int n) {
    __shared__ int s[256];
    int t = threadIdx.x;
    int i = blockIdx.x * 256 + t;
    int v = (i < n) ? x[i] : 0;
    s[t] = v; __syncthreads();
    #pragma unroll
    for (int off = 1; off < 256; off <<= 1) {
        int u = (t >= off) ? s[t - off] : 0;
        __syncthreads();
        s[t] += u;
        __syncthreads();
    }
    if (i < n) excl[i] = s[t] - v;
    if (t == 255) bsum[blockIdx.x] = s[255];
}
__global__ void k_scan2(int* __restrict__ bsum, int* __restrict__ boff, int nb) {
    __shared__ int s[256];
    int t = threadIdx.x;
    int v = (t < nb) ? bsum[t] : 0;
    s[t] = v; __syncthreads();
    #pragma unroll
    for (int off = 1; off < 256; off <<= 1) {
        int u = (t >= off) ? s[t - off] : 0;
        __syncthreads();
        s[t] += u;
        __syncthreads();
    }
    if (t < nb) boff[t] = s[t] - v;
}
__global__ void k_scan3(const int* __restrict__ excl, const int* __restrict__ boff,
                        int* __restrict__ rowptr) {
    int i = blockIdx.x * blockDim.x + threadIdx.x;
    if (i < NN) rowptr[i] = excl[i] + boff[i >> 8];
    else if (i == NN) rowptr[NN] = EE;
}
__global__ void k_scatter_ids(const int* __restrict__ src, const int* __restrict__ dst,
                              const int* __restrict__ rowptr, int* __restrict__ fill,
                              int* __restrict__ srcs_csr) {
    int e = blockIdx.x * blockDim.x + threadIdx.x;
    if (e >= EE) return;
    int d = dst[e];
    int slot = atomicAdd(&fill[d], 1);
    srcs_csr[rowptr[d] + slot] = src[e];
}

__device__ __forceinline__ float4 f4add(float4 a, float4 b) {
    return make_float4(a.x + b.x, a.y + b.y, a.z + b.z, a.w + b.w);
}

// ================= GIN gather: wave per node, 4 edges concurrent =================
// 16-lane group x float4 channels; group g handles edges r0+g, r0+g+4, ...
__global__ void k_gin_gather(const float* __restrict__ h, const int* __restrict__ rowptr,
                             const int* __restrict__ srcs_csr, float* __restrict__ out) {
    int v = (int)((blockIdx.x * (long)blockDim.x + threadIdx.x) >> 6);
    if (v >= NN) return;
    int lw = threadIdx.x & 63;
    int g = lw >> 4, li = lw & 15;
    int c4 = li * 4;
    float4 acc = make_float4(0.f, 0.f, 0.f, 0.f);
    if (g == 0) acc = *(const float4*)&h[(long)v * 64 + c4];  // self term
    int r0 = rowptr[v], r1 = rowptr[v + 1];
    for (int j = r0 + g; j < r1; j += 4) {
        int s = srcs_csr[j];
        acc = f4add(acc, *(const float4*)&h[(long)s * 64 + c4]);
    }
    // merge the 4 groups (lanes xor 16, 32 hold the same channels)
    #pragma unroll
    for (int off = 16; off < 64; off <<= 1) {
        acc.x += __shfl_xor(acc.x, off);
        acc.y += __shfl_xor(acc.y, off);
        acc.z += __shfl_xor(acc.z, off);
        acc.w += __shfl_xor(acc.w, off);
    }
    if (g == 0) *(float4*)&out[(long)v * 64 + c4] = acc;
}

// ---------------- register-tiled SGEMM: out = act(bn(A @ W + bias)) ----
// 256 threads -> 64 rows x 64 cols (blockIdx.y = col tile). 4x4 micro-tile.
template<int K, int M, bool BN, bool RELU>
__global__ __launch_bounds__(256)
void k_mm(const float* __restrict__ A,
          const float* __restrict__ W, const float* __restrict__ bias,
          const float* __restrict__ bng, const float* __restrict__ bnb,
          const float* __restrict__ bnm, const float* __restrict__ bnv,
          float* __restrict__ out, int n) {
    constexpr int KB = 16;
    __shared__ float As[64][KB + 4];
    __shared__ float Ws[KB][64];
    const int tid  = threadIdx.x;
    const int tx   = tid & 15;
    const int ty   = tid >> 4;
    const int row0 = blockIdx.x * 64;
    const int col0 = blockIdx.y * 64;

    float acc[4][4];
    #pragma unroll
    for (int i = 0; i < 4; ++i)
        { acc[i][0] = 0.f; acc[i][1] = 0.f; acc[i][2] = 0.f; acc[i][3] = 0.f; }

    for (int kb = 0; kb < K; kb += KB) {
        {
            int r = tid >> 2, c4 = (tid & 3) * 4;
            int row = row0 + r;
            float4 v = make_float4(0.f, 0.f, 0.f, 0.f);
            if (row < n) v = *(const float4*)&A[(long)row * K + kb + c4];
            *(float4*)&As[r][c4] = v;
        }
        {
            int wk = tid >> 4, wm4 = (tid & 15) * 4;
            *(float4*)&Ws[wk][wm4] = *(const float4*)&W[(long)(kb + wk) * M + col0 + wm4];
        }
        __syncthreads();
        #pragma unroll
        for (int kk = 0; kk < KB; ++kk) {
            float4 w = *(const float4*)&Ws[kk][tx * 4];
            #pragma unroll
            for (int i = 0; i < 4; ++i) {
                float av = As[i * 16 + ty][kk];
                acc[i][0] += av * w.x;
                acc[i][1] += av * w.y;
                acc[i][2] += av * w.z;
                acc[i][3] += av * w.w;
            }
        }
        __syncthreads();
    }

    const int c0 = col0 + tx * 4;
    float4 bb = *(const float4*)&bias[c0];
    float4 sc, sh;
    if (BN) {
        float4 g = *(const float4*)&bng[c0];
        float4 b = *(const float4*)&bnb[c0];
        float4 m = *(const float4*)&bnm[c0];
        float4 vv = *(const float4*)&bnv[c0];
        sc.x = g.x * rsqrtf(vv.x + BN_EPS_C); sc.y = g.y * rsqrtf(vv.y + BN_EPS_C);
        sc.z = g.z * rsqrtf(vv.z + BN_EPS_C); sc.w = g.w * rsqrtf(vv.w + BN_EPS_C);
        sh.x = b.x - m.x * sc.x; sh.y = b.y - m.y * sc.y;
        sh.z = b.z - m.z * sc.z; sh.w = b.w - m.w * sc.w;
    }
    #pragma unroll
    for (int i = 0; i < 4; ++i) {
        int row = row0 + i * 16 + ty;
        if (row >= n) continue;
        float4 v;
        v.x = acc[i][0] + bb.x; v.y = acc[i][1] + bb.y;
        v.z = acc[i][2] + bb.z; v.w = acc[i][3] + bb.w;
        if (BN) {
            v.x = v.x * sc.x + sh.x; v.y = v.y * sc.y + sh.y;
            v.z = v.z * sc.z + sh.z; v.w = v.w * sc.w + sh.w;
        }
        if (RELU) {
            v.x = fmaxf(v.x, 0.f); v.y = fmaxf(v.y, 0.f);
            v.z = fmaxf(v.z, 0.f); v.w = fmaxf(v.w, 0.f);
        }
        *(float4*)&out[(long)row * M + c0] = v;
    }
}

// ================= GATv2 fused: single-pass online softmax, 4 edges/wave =================
// wave h = head h. Within a wave: 4 groups of 16 lanes; lane owns 4 channels (float4).
// Group g processes edges r0+g, r0+g+4, ... with flash-style online rescale of acc.
// Branchless update; group-partials merged via shfl_xor(16|32) at the end.
template<int HH, int M>
__global__ void k_gat_fused(const float* __restrict__ xl, const float* __restrict__ xr,
                            const float* __restrict__ att, const int* __restrict__ rowptr,
                            const int* __restrict__ srcs_csr,
                            const float* __restrict__ bias, float* __restrict__ out) {
    int v = blockIdx.x;
    int h = threadIdx.x >> 6;            // wave index = head
    int lw = threadIdx.x & 63;
    int g = lw >> 4, li = lw & 15;
    int c4 = h * 64 + li * 4;
    float4 att4 = *(const float4*)&att[c4];
    float4 xl_v = *(const float4*)&xl[(long)v * M + c4];
    float4 xr_v = *(const float4*)&xr[(long)v * M + c4];

    // self-loop alpha (all groups compute; used as common init for m)
    float4 t4;
    t4.x = xl_v.x + xr_v.x; t4.x = (t4.x > 0.f) ? t4.x : NEG_SLOPE * t4.x;
    t4.y = xl_v.y + xr_v.y; t4.y = (t4.y > 0.f) ? t4.y : NEG_SLOPE * t4.y;
    t4.z = xl_v.z + xr_v.z; t4.z = (t4.z > 0.f) ? t4.z : NEG_SLOPE * t4.z;
    t4.w = xl_v.w + xr_v.w; t4.w = (t4.w > 0.f) ? t4.w : NEG_SLOPE * t4.w;
    float a = t4.x * att4.x + t4.y * att4.y + t4.z * att4.z + t4.w * att4.w;
    #pragma unroll
    for (int off = 1; off < 16; off <<= 1) a += __shfl_xor(a, off);

    float m = a;                                   // identical in all groups
    float den = (g == 0) ? 1.0f : 0.0f;            // self term lives in group 0
    float4 acc = (g == 0) ? xl_v : make_float4(0.f, 0.f, 0.f, 0.f);

    const int r0 = rowptr[v], r1 = rowptr[v + 1];
    for (int j = r0 + g; j < r1; j += 4) {
        int s = srcs_csr[j];
        float4 xs = *(const float4*)&xl[(long)s * M + c4];
        float4 u;
        u.x = xs.x + xr_v.x; u.x = (u.x > 0.f) ? u.x : NEG_SLOPE * u.x;
        u.y = xs.y + xr_v.y; u.y = (u.y > 0.f) ? u.y : NEG_SLOPE * u.y;
        u.z = xs.z + xr_v.z; u.z = (u.z > 0.f) ? u.z : NEG_SLOPE * u.z;
        u.w = xs.w + xr_v.w; u.w = (u.w > 0.f) ? u.w : NEG_SLOPE * u.w;
        float a2 = u.x * att4.x + u.y * att4.y + u.z * att4.z + u.w * att4.w;
        #pragma unroll
        for (int off = 1; off < 16; off <<= 1) a2 += __shfl_xor(a2, off);
        // branchless online update
        float mn = fmaxf(m, a2);
        float s1 = __expf(m - mn);    // 1 when m is the max
        float e  = __expf(a2 - mn);   // 1 when a2 is the max
        den = den * s1 + e;
        acc.x = acc.x * s1 + e * xs.x;
        acc.y = acc.y * s1 + e * xs.y;
        acc.z = acc.z * s1 + e * xs.z;
        acc.w = acc.w * s1 + e * xs.w;
        m = mn;
    }
    // merge the 4 group-partials (lanes xor 16/32 hold the same channels)
    #pragma unroll
    for (int off = 16; off < 64; off <<= 1) {
        float m2 = __shfl_xor(m, off);
        float d2 = __shfl_xor(den, off);
        float ax = __shfl_xor(acc.x, off);
        float ay = __shfl_xor(acc.y, off);
        float az = __shfl_xor(acc.z, off);
        float aw = __shfl_xor(acc.w, off);
        float mn = fmaxf(m, m2);
        float s1 = __expf(m - mn), s2 = __expf(m2 - mn);
        den = den * s1 + d2 * s2;
        acc.x = acc.x * s1 + ax * s2;
        acc.y = acc.y * s1 + ay * s2;
        acc.z = acc.z * s1 + az * s2;
        acc.w = acc.w * s1 + aw * s2;
        m = mn;
    }
    if (g == 0) {
        float4 b4 = *(const float4*)&bias[c4];
        float inv = 1.0f / (den + 1e-16f);
        float4 o;
        o.x = fmaxf(acc.x * inv + b4.x, 0.f);
        o.y = fmaxf(acc.y * inv + b4.y, 0.f);
        o.z = fmaxf(acc.z * inv + b4.z, 0.f);
        o.w = fmaxf(acc.w * inv + b4.w, 0.f);
        *(float4*)&out[(long)v * M + c4] = o;
    }
}

// ---------------- mean pool (atomics) ----------------
__global__ void k_pool(const float* __restrict__ gin, const float* __restrict__ gat,
                       const int* __restrict__ batch, float* __restrict__ pooled,
                       float* __restrict__ counts) {
    int i = blockIdx.x * blockDim.x + threadIdx.x;
    if (i >= NN * 128) return;
    int v = i >> 7, c = i & 127;
    int g = batch[v];
    float val = (c < 64) ? gin[v * 64 + c] : gat[v * 64 + (c - 64)];
    atomicAdd(&pooled[g * 128 + c], val);
    if (c == 0) atomicAdd(&counts[g], 1.0f);
}

// ---------------- graph head ----------------
__global__ void k_head(const float* __restrict__ pooled, const float* __restrict__ counts,
                       const float* __restrict__ gw, const float* __restrict__ gb,
                       const float* __restrict__ cw, const float* __restrict__ cb,
                       float* __restrict__ out) {
    int g = blockIdx.x;
    int j = threadIdx.x;      // 64 threads = 1 wave
    __shared__ float prow[128];
    float cnt = fmaxf(counts[g], 1.0f);
    prow[j]      = pooled[g * 128 + j] / cnt;
    prow[j + 64] = pooled[g * 128 + 64 + j] / cnt;
    __syncthreads();
    float acc = gb[j];
    #pragma unroll
    for (int k = 0; k < 128; ++k) acc += prow[k] * gw[k * 64 + j];
    out[GG + g * 65 + j] = acc;
    if (j == 0) out[GG + g * 65 + 64] = 0.0f;     // lovasz stub
    float p = acc * cw[j];
    #pragma unroll
    for (int off = 32; off; off >>= 1) p += __shfl_xor(p, off);
    if (j == 0) out[g] = p + cb[0];
}

// ---------------- host launcher ----------------
extern "C" void kernel_launch(void* const* d_in, const int* in_sizes, int n_in,
                              void* d_out, int out_size, void* d_ws, size_t ws_size,
                              hipStream_t stream) {
    const float* x        = (const float*)d_in[0];
    const int*   ei       = (const int*)d_in[1];
    const int*   src      = ei;
    const int*   dst      = ei + EE;
    const int*   batch    = (const int*)d_in[2];
    const float* gin_w1   = (const float*)d_in[3];
    const float* gin_b1   = (const float*)d_in[4];
    const float* gin_bn_g = (const float*)d_in[5];
    const float* gin_bn_b = (const float*)d_in[6];
    const float* gin_bn_m = (const float*)d_in[7];
    const float* gin_bn_v = (const float*)d_in[8];
    const float* gin_w2   = (const float*)d_in[9];
    const float* gin_b2   = (const float*)d_in[10];
    const float* gat_wl[3]   = {(const float*)d_in[11], (const float*)d_in[17], (const float*)d_in[23]};
    const float* gat_bl[3]   = {(const float*)d_in[12], (const float*)d_in[18], (const float*)d_in[24]};
    const float* gat_wr[3]   = {(const float*)d_in[13], (const float*)d_in[19], (const float*)d_in[25]};
    const float* gat_br[3]   = {(const float*)d_in[14], (const float*)d_in[20], (const float*)d_in[26]};
    const float* gat_att[3]  = {(const float*)d_in[15], (const float*)d_in[21], (const float*)d_in[27]};
    const float* gat_bias[3] = {(const float*)d_in[16], (const float*)d_in[22], (const float*)d_in[28]};
    const float* graph_w  = (const float*)d_in[29];
    const float* graph_b  = (const float*)d_in[30];
    const float* clf_w    = (const float*)d_in[31];
    const float* clf_b    = (const float*)d_in[32];
    float* out = (float*)d_out;

    // ---- workspace carve-up (16B-aligned chunks) ----
    float* ws = (float*)d_ws;
    size_t o = 0;
    auto alloc = [&](size_t n) { float* p = ws + o; o += (n + 3) & ~(size_t)3; return p; };
    float* gin_h    = alloc((size_t)NN * 64);
    float* gin_hsum = alloc((size_t)NN * 64);
    float* gin_tmp  = alloc((size_t)NN * 64);
    float* gat_h    = alloc((size_t)NN * 128);
    float* gat_xl   = alloc((size_t)NN * 128);
    float* gat_xr   = alloc((size_t)NN * 128);
    float* gat_out  = alloc((size_t)NN * 64);
    float* pooled   = alloc((size_t)GG * 128);
    float* counts   = alloc((size_t)GG);
    int* deg      = (int*)alloc((size_t)NN);
    int* fillc    = (int*)alloc((size_t)NN);
    int* excl     = (int*)alloc((size_t)NN);
    int* rowptr   = (int*)alloc((size_t)NN + 1);
    int* bsum     = (int*)alloc(256);
    int* boff     = (int*)alloc(256);
    int* srcs_csr = (int*)alloc((size_t)EE);
    (void)ws_size; (void)n_in; (void)in_sizes; (void)out_size;

    const int TB = 256;
    const int NB_SCAN = cdiv(NN, 256);   // 196

    // =================== CSR build (shared by GIN + GAT) ===================
    k_filli<<<cdiv(NN, TB), TB, 0, stream>>>(deg, 0, NN);
    k_filli<<<cdiv(NN, TB), TB, 0, stream>>>(fillc, 0, NN);
    k_count<<<cdiv(EE, TB), TB, 0, stream>>>(dst, deg);
    k_scan1<<<NB_SCAN, 256, 0, stream>>>(deg, excl, bsum, NN);
    k_scan2<<<1, 256, 0, stream>>>(bsum, boff, NB_SCAN);
    k_scan3<<<cdiv(NN + 1, TB), TB, 0, stream>>>(excl, boff, rowptr);
    k_scatter_ids<<<cdiv(EE, TB), TB, 0, stream>>>(src, dst, rowptr, fillc, srcs_csr);

    const int NR = cdiv(NN, 64);         // 782 row-blocks

    // =================== GIN encoder ===================
    const float* hin = x;
    for (int l = 0; l < 3; ++l) {
        k_gin_gather<<<cdiv((long)NN * 64, TB), TB, 0, stream>>>(hin, rowptr, srcs_csr, gin_hsum);
        k_mm<64, 64, true, true><<<dim3(NR, 1), 256, 0, stream>>>(
            gin_hsum, gin_w1 + l * 4096, gin_b1 + l * 64,
            gin_bn_g + l * 64, gin_bn_b + l * 64, gin_bn_m + l * 64, gin_bn_v + l * 64,
            gin_tmp, NN);
        k_mm<64, 64, false, true><<<dim3(NR, 1), 256, 0, stream>>>(
            gin_tmp, gin_w2 + l * 4096, gin_b2 + l * 64,
            nullptr, nullptr, nullptr, nullptr, gin_h, NN);
        hin = gin_h;
    }

    // =================== GATv2 encoder ===================
    const float* hg = x;
    for (int l = 0; l < 3; ++l) {
        if (l == 0) {
            k_mm<64, 128, false, false><<<dim3(NR, 2), 256, 0, stream>>>(
                hg, gat_wl[l], gat_bl[l], nullptr, nullptr, nullptr, nullptr, gat_xl, NN);
            k_mm<64, 128, false, false><<<dim3(NR, 2), 256, 0, stream>>>(
                hg, gat_wr[l], gat_br[l], nullptr, nullptr, nullptr, nullptr, gat_xr, NN);
            k_gat_fused<2, 128><<<NN, 128, 0, stream>>>(
                gat_xl, gat_xr, gat_att[l], rowptr, srcs_csr, gat_bias[l], gat_h);
            hg = gat_h;
        } else if (l == 1) {
            k_mm<128, 128, false, false><<<dim3(NR, 2), 256, 0, stream>>>(
                hg, gat_wl[l], gat_bl[l], nullptr, nullptr, nullptr, nullptr, gat_xl, NN);
            k_mm<128, 128, false, false><<<dim3(NR, 2), 256, 0, stream>>>(
                hg, gat_wr[l], gat_br[l], nullptr, nullptr, nullptr, nullptr, gat_xr, NN);
            k_gat_fused<2, 128><<<NN, 128, 0, stream>>>(
                gat_xl, gat_xr, gat_att[l], rowptr, srcs_csr, gat_bias[l], gat_h);
            hg = gat_h;
        } else {
            k_mm<128, 64, false, false><<<dim3(NR, 1), 256, 0, stream>>>(
                hg, gat_wl[l], gat_bl[l], nullptr, nullptr, nullptr, nullptr, gat_xl, NN);
            k_mm<128, 64, false, false><<<dim3(NR, 1), 256, 0, stream>>>(
                hg, gat_wr[l], gat_br[l], nullptr, nullptr, nullptr, nullptr, gat_xr, NN);
            k_gat_fused<1, 64><<<NN, 64, 0, stream>>>(
                gat_xl, gat_xr, gat_att[l], rowptr, srcs_csr, gat_bias[l], gat_out);
        }
    }

    // =================== pool + heads ===================
    k_fill<<<cdiv((long)GG * 129, TB), TB, 0, stream>>>(pooled, 0.0f, GG * 129); // pooled+counts contiguous
    k_pool<<<cdiv((long)NN * 128, TB), TB, 0, stream>>>(gin_h, gat_out, batch, pooled, counts);
    k_head<<<GG, 64, 0, stream>>>(pooled, counts, graph_w, graph_b, clf_w, clf_b, out);
}

// Round 16
// 703.099 us; speedup vs baseline: 6.3558x; 1.2338x over previous
//
#include <hip/hip_runtime.h>
#include <math.h>

// ---------------- problem constants (fixed by the reference) ----------------
#define NN 50000
#define EE 800000
#define GG 256
constexpr float NEG_SLOPE = 0.2f;
constexpr float BN_EPS_C  = 1e-5f;

static inline int cdiv(long a, long b) { return (int)((a + b - 1) / b); }

// ---------------- small utility kernels ----------------
__global__ void k_filli(int* __restrict__ p, int v, int n) {
    int i = blockIdx.x * blockDim.x + threadIdx.x;
    if (i < n) p[i] = v;
}

// ================= CSR build: deg -> rowptr(scan) -> slot scatter =================
__global__ void k_count(const int* __restrict__ dst, int* __restrict__ deg) {
    int e = blockIdx.x * blockDim.x + threadIdx.x;
    if (e < EE) atomicAdd(&deg[dst[e]], 1);
}

__global__ void k_scan1(const int* __restrict__ x, int* __restrict__ excl,
                        int* __restrict__ bsum, int n) {
    __shared__ int s[256];
    int t = threadIdx.x;
    int i = blockIdx.x * 256 + t;
    int v = (i < n) ? x[i] : 0;
    s[t] = v; __syncthreads();
    #pragma unroll
    for (int off = 1; off < 256; off <<= 1) {
        int u = (t >= off) ? s[t - off] : 0;
        __syncthreads();
        s[t] += u;
        __syncthreads();
    }
    if (i < n) excl[i] = s[t] - v;
    if (t == 255) bsum[blockIdx.x] = s[255];
}
__global__ void k_scan2(int* __restrict__ bsum, int* __restrict__ boff, int nb) {
    __shared__ int s[256];
    int t = threadIdx.x;
    int v = (t < nb) ? bsum[t] : 0;
    s[t] = v; __syncthreads();
    #pragma unroll
    for (int off = 1; off < 256; off <<= 1) {
        int u = (t >= off) ? s[t - off] : 0;
        __syncthreads();
        s[t] += u;
        __syncthreads();
    }
    if (t < nb) boff[t] = s[t] - v;
}
__global__ void k_scan3(const int* __restrict__ excl, const int* __restrict__ boff,
                        int* __restrict__ rowptr) {
    int i = blockIdx.x * blockDim.x + threadIdx.x;
    if (i < NN) rowptr[i] = excl[i] + boff[i >> 8];
    else if (i == NN) rowptr[NN] = EE;
}
__global__ void k_scatter_ids(const int* __restrict__ src, const int* __restrict__ dst,
                              const int* __restrict__ rowptr, int* __restrict__ fill,
                              int* __restrict__ srcs_csr) {
    int e = blockIdx.x * blockDim.x + threadIdx.x;
    if (e >= EE) return;
    int d = dst[e];
    int slot = atomicAdd(&fill[d], 1);
    srcs_csr[rowptr[d] + slot] = src[e];
}

__device__ __forceinline__ float4 f4add(float4 a, float4 b) {
    return make_float4(a.x + b.x, a.y + b.y, a.z + b.z, a.w + b.w);
}

// ================= GIN gather: wave per node, 4 edges concurrent =================
// 16-lane group x float4 channels; group g handles edges r0+g, r0+g+4, ...
__global__ void k_gin_gather(const float* __restrict__ h, const int* __restrict__ rowptr,
                             const int* __restrict__ srcs_csr, float* __restrict__ out) {
    int v = (int)((blockIdx.x * (long)blockDim.x + threadIdx.x) >> 6);
    if (v >= NN) return;
    int lw = threadIdx.x & 63;
    int g = lw >> 4, li = lw & 15;
    int c4 = li * 4;
    float4 acc = make_float4(0.f, 0.f, 0.f, 0.f);
    if (g == 0) acc = *(const float4*)&h[(long)v * 64 + c4];  // self term
    int r0 = rowptr[v], r1 = rowptr[v + 1];
    for (int j = r0 + g; j < r1; j += 4) {
        int s = srcs_csr[j];
        acc = f4add(acc, *(const float4*)&h[(long)s * 64 + c4]);
    }
    // merge the 4 groups (lanes xor 16, 32 hold the same channels)
    #pragma unroll
    for (int off = 16; off < 64; off <<= 1) {
        acc.x += __shfl_xor(acc.x, off);
        acc.y += __shfl_xor(acc.y, off);
        acc.z += __shfl_xor(acc.z, off);
        acc.w += __shfl_xor(acc.w, off);
    }
    if (g == 0) *(float4*)&out[(long)v * 64 + c4] = acc;
}

// ---------------- register-tiled SGEMM: out = act(bn(A @ W + bias)) ----
// 256 threads -> 64 rows x 64 cols (blockIdx.y = col tile). 4x4 micro-tile.
template<int K, int M, bool BN, bool RELU>
__global__ __launch_bounds__(256)
void k_mm(const float* __restrict__ A,
          const float* __restrict__ W, const float* __restrict__ bias,
          const float* __restrict__ bng, const float* __restrict__ bnb,
          const float* __restrict__ bnm, const float* __restrict__ bnv,
          float* __restrict__ out, int n) {
    constexpr int KB = 16;
    __shared__ float As[64][KB + 4];
    __shared__ float Ws[KB][64];
    const int tid  = threadIdx.x;
    const int tx   = tid & 15;
    const int ty   = tid >> 4;
    const int row0 = blockIdx.x * 64;
    const int col0 = blockIdx.y * 64;

    float acc[4][4];
    #pragma unroll
    for (int i = 0; i < 4; ++i)
        { acc[i][0] = 0.f; acc[i][1] = 0.f; acc[i][2] = 0.f; acc[i][3] = 0.f; }

    for (int kb = 0; kb < K; kb += KB) {
        {
            int r = tid >> 2, c4 = (tid & 3) * 4;
            int row = row0 + r;
            float4 v = make_float4(0.f, 0.f, 0.f, 0.f);
            if (row < n) v = *(const float4*)&A[(long)row * K + kb + c4];
            *(float4*)&As[r][c4] = v;
        }
        {
            int wk = tid >> 4, wm4 = (tid & 15) * 4;
            *(float4*)&Ws[wk][wm4] = *(const float4*)&W[(long)(kb + wk) * M + col0 + wm4];
        }
        __syncthreads();
        #pragma unroll
        for (int kk = 0; kk < KB; ++kk) {
            float4 w = *(const float4*)&Ws[kk][tx * 4];
            #pragma unroll
            for (int i = 0; i < 4; ++i) {
                float av = As[i * 16 + ty][kk];
                acc[i][0] += av * w.x;
                acc[i][1] += av * w.y;
                acc[i][2] += av * w.z;
                acc[i][3] += av * w.w;
            }
        }
        __syncthreads();
    }

    const int c0 = col0 + tx * 4;
    float4 bb = *(const float4*)&bias[c0];
    float4 sc, sh;
    if (BN) {
        float4 g = *(const float4*)&bng[c0];
        float4 b = *(const float4*)&bnb[c0];
        float4 m = *(const float4*)&bnm[c0];
        float4 vv = *(const float4*)&bnv[c0];
        sc.x = g.x * rsqrtf(vv.x + BN_EPS_C); sc.y = g.y * rsqrtf(vv.y + BN_EPS_C);
        sc.z = g.z * rsqrtf(vv.z + BN_EPS_C); sc.w = g.w * rsqrtf(vv.w + BN_EPS_C);
        sh.x = b.x - m.x * sc.x; sh.y = b.y - m.y * sc.y;
        sh.z = b.z - m.z * sc.z; sh.w = b.w - m.w * sc.w;
    }
    #pragma unroll
    for (int i = 0; i < 4; ++i) {
        int row = row0 + i * 16 + ty;
        if (row >= n) continue;
        float4 v;
        v.x = acc[i][0] + bb.x; v.y = acc[i][1] + bb.y;
        v.z = acc[i][2] + bb.z; v.w = acc[i][3] + bb.w;
        if (BN) {
            v.x = v.x * sc.x + sh.x; v.y = v.y * sc.y + sh.y;
            v.z = v.z * sc.z + sh.z; v.w = v.w * sc.w + sh.w;
        }
        if (RELU) {
            v.x = fmaxf(v.x, 0.f); v.y = fmaxf(v.y, 0.f);
            v.z = fmaxf(v.z, 0.f); v.w = fmaxf(v.w, 0.f);
        }
        *(float4*)&out[(long)row * M + c0] = v;
    }
}

// ================= GATv2 fused: single-pass online softmax, 4 edges/wave =================
// wave h = head h. Within a wave: 4 groups of 16 lanes; lane owns 4 channels (float4).
// Group g processes edges r0+g, r0+g+4, ... with flash-style online rescale of acc.
// Branchless update; group-partials merged via shfl_xor(16|32) at the end.
template<int HH, int M>
__global__ void k_gat_fused(const float* __restrict__ xl, const float* __restrict__ xr,
                            const float* __restrict__ att, const int* __restrict__ rowptr,
                            const int* __restrict__ srcs_csr,
                            const float* __restrict__ bias, float* __restrict__ out) {
    int v = blockIdx.x;
    int h = threadIdx.x >> 6;            // wave index = head
    int lw = threadIdx.x & 63;
    int g = lw >> 4, li = lw & 15;
    int c4 = h * 64 + li * 4;
    float4 att4 = *(const float4*)&att[c4];
    float4 xl_v = *(const float4*)&xl[(long)v * M + c4];
    float4 xr_v = *(const float4*)&xr[(long)v * M + c4];

    // self-loop alpha (all groups compute; used as common init for m)
    float4 t4;
    t4.x = xl_v.x + xr_v.x; t4.x = (t4.x > 0.f) ? t4.x : NEG_SLOPE * t4.x;
    t4.y = xl_v.y + xr_v.y; t4.y = (t4.y > 0.f) ? t4.y : NEG_SLOPE * t4.y;
    t4.z = xl_v.z + xr_v.z; t4.z = (t4.z > 0.f) ? t4.z : NEG_SLOPE * t4.z;
    t4.w = xl_v.w + xr_v.w; t4.w = (t4.w > 0.f) ? t4.w : NEG_SLOPE * t4.w;
    float a = t4.x * att4.x + t4.y * att4.y + t4.z * att4.z + t4.w * att4.w;
    #pragma unroll
    for (int off = 1; off < 16; off <<= 1) a += __shfl_xor(a, off);

    float m = a;                                   // identical in all groups
    float den = (g == 0) ? 1.0f : 0.0f;            // self term lives in group 0
    float4 acc = (g == 0) ? xl_v : make_float4(0.f, 0.f, 0.f, 0.f);

    const int r0 = rowptr[v], r1 = rowptr[v + 1];
    for (int j = r0 + g; j < r1; j += 4) {
        int s = srcs_csr[j];
        float4 xs = *(const float4*)&xl[(long)s * M + c4];
        float4 u;
        u.x = xs.x + xr_v.x; u.x = (u.x > 0.f) ? u.x : NEG_SLOPE * u.x;
        u.y = xs.y + xr_v.y; u.y = (u.y > 0.f) ? u.y : NEG_SLOPE * u.y;
        u.z = xs.z + xr_v.z; u.z = (u.z > 0.f) ? u.z : NEG_SLOPE * u.z;
        u.w = xs.w + xr_v.w; u.w = (u.w > 0.f) ? u.w : NEG_SLOPE * u.w;
        float a2 = u.x * att4.x + u.y * att4.y + u.z * att4.z + u.w * att4.w;
        #pragma unroll
        for (int off = 1; off < 16; off <<= 1) a2 += __shfl_xor(a2, off);
        // branchless online update
        float mn = fmaxf(m, a2);
        float s1 = __expf(m - mn);    // 1 when m is the max
        float e  = __expf(a2 - mn);   // 1 when a2 is the max
        den = den * s1 + e;
        acc.x = acc.x * s1 + e * xs.x;
        acc.y = acc.y * s1 + e * xs.y;
        acc.z = acc.z * s1 + e * xs.z;
        acc.w = acc.w * s1 + e * xs.w;
        m = mn;
    }
    // merge the 4 group-partials (lanes xor 16/32 hold the same channels)
    #pragma unroll
    for (int off = 16; off < 64; off <<= 1) {
        float m2 = __shfl_xor(m, off);
        float d2 = __shfl_xor(den, off);
        float ax = __shfl_xor(acc.x, off);
        float ay = __shfl_xor(acc.y, off);
        float az = __shfl_xor(acc.z, off);
        float aw = __shfl_xor(acc.w, off);
        float mn = fmaxf(m, m2);
        float s1 = __expf(m - mn), s2 = __expf(m2 - mn);
        den = den * s1 + d2 * s2;
        acc.x = acc.x * s1 + ax * s2;
        acc.y = acc.y * s1 + ay * s2;
        acc.z = acc.z * s1 + az * s2;
        acc.w = acc.w * s1 + aw * s2;
        m = mn;
    }
    if (g == 0) {
        float4 b4 = *(const float4*)&bias[c4];
        float inv = 1.0f / (den + 1e-16f);
        float4 o;
        o.x = fmaxf(acc.x * inv + b4.x, 0.f);
        o.y = fmaxf(acc.y * inv + b4.y, 0.f);
        o.z = fmaxf(acc.z * inv + b4.z, 0.f);
        o.w = fmaxf(acc.w * inv + b4.w, 0.f);
        *(float4*)&out[(long)v * M + c4] = o;
    }
}

// ================= graph ranges: batch is SORTED -> binary search boundaries =========
__global__ void k_gstart(const int* __restrict__ batch, int* __restrict__ gstart) {
    int g = threadIdx.x;                  // 256 threads, 1 block
    int lo = 0, hi = NN;
    while (lo < hi) { int mid = (lo + hi) >> 1; if (batch[mid] < g) lo = mid + 1; else hi = mid; }
    gstart[g] = lo;
    if (g == 0) gstart[GG] = NN;
}

// ================= segmented mean pool: one block per graph, zero atomics =============
// 512 threads = 4 node-lanes x 128 channels. Writes the MEAN directly.
// (R15 post-mortem: atomic k_pool was 172 us with 195-way address contention.)
__global__ __launch_bounds__(512)
void k_pool_seg(const float* __restrict__ gin, const float* __restrict__ gat,
                const int* __restrict__ gstart, float* __restrict__ pooled) {
    int g = blockIdx.x;
    int tid = threadIdx.x;
    int nl = tid >> 7, c = tid & 127;     // node-lane, channel
    int v0 = gstart[g], v1 = gstart[g + 1];
    float acc = 0.f;
    for (int v = v0 + nl; v < v1; v += 4)
        acc += (c < 64) ? gin[(long)v * 64 + c] : gat[(long)v * 64 + (c - 64)];
    __shared__ float sacc[512];
    sacc[tid] = acc;
    __syncthreads();
    if (nl == 0) {
        float s = sacc[c] + sacc[c + 128] + sacc[c + 256] + sacc[c + 384];
        float cnt = fmaxf((float)(v1 - v0), 1.0f);
        pooled[g * 128 + c] = s / cnt;
    }
}

// ---------------- graph head (pooled already holds the mean) ----------------
__global__ void k_head(const float* __restrict__ pooled,
                       const float* __restrict__ gw, const float* __restrict__ gb,
                       const float* __restrict__ cw, const float* __restrict__ cb,
                       float* __restrict__ out) {
    int g = blockIdx.x;
    int j = threadIdx.x;      // 64 threads = 1 wave
    __shared__ float prow[128];
    prow[j]      = pooled[g * 128 + j];
    prow[j + 64] = pooled[g * 128 + 64 + j];
    __syncthreads();
    float acc = gb[j];
    #pragma unroll
    for (int k = 0; k < 128; ++k) acc += prow[k] * gw[k * 64 + j];
    out[GG + g * 65 + j] = acc;
    if (j == 0) out[GG + g * 65 + 64] = 0.0f;     // lovasz stub
    float p = acc * cw[j];
    #pragma unroll
    for (int off = 32; off; off >>= 1) p += __shfl_xor(p, off);
    if (j == 0) out[g] = p + cb[0];
}

// ---------------- host launcher ----------------
extern "C" void kernel_launch(void* const* d_in, const int* in_sizes, int n_in,
                              void* d_out, int out_size, void* d_ws, size_t ws_size,
                              hipStream_t stream) {
    const float* x        = (const float*)d_in[0];
    const int*   ei       = (const int*)d_in[1];
    const int*   src      = ei;
    const int*   dst      = ei + EE;
    const int*   batch    = (const int*)d_in[2];
    const float* gin_w1   = (const float*)d_in[3];
    const float* gin_b1   = (const float*)d_in[4];
    const float* gin_bn_g = (const float*)d_in[5];
    const float* gin_bn_b = (const float*)d_in[6];
    const float* gin_bn_m = (const float*)d_in[7];
    const float* gin_bn_v = (const float*)d_in[8];
    const float* gin_w2   = (const float*)d_in[9];
    const float* gin_b2   = (const float*)d_in[10];
    const float* gat_wl[3]   = {(const float*)d_in[11], (const float*)d_in[17], (const float*)d_in[23]};
    const float* gat_bl[3]   = {(const float*)d_in[12], (const float*)d_in[18], (const float*)d_in[24]};
    const float* gat_wr[3]   = {(const float*)d_in[13], (const float*)d_in[19], (const float*)d_in[25]};
    const float* gat_br[3]   = {(const float*)d_in[14], (const float*)d_in[20], (const float*)d_in[26]};
    const float* gat_att[3]  = {(const float*)d_in[15], (const float*)d_in[21], (const float*)d_in[27]};
    const float* gat_bias[3] = {(const float*)d_in[16], (const float*)d_in[22], (const float*)d_in[28]};
    const float* graph_w  = (const float*)d_in[29];
    const float* graph_b  = (const float*)d_in[30];
    const float* clf_w    = (const float*)d_in[31];
    const float* clf_b    = (const float*)d_in[32];
    float* out = (float*)d_out;

    // ---- workspace carve-up (16B-aligned chunks) ----
    float* ws = (float*)d_ws;
    size_t o = 0;
    auto alloc = [&](size_t n) { float* p = ws + o; o += (n + 3) & ~(size_t)3; return p; };
    float* gin_h    = alloc((size_t)NN * 64);
    float* gin_hsum = alloc((size_t)NN * 64);
    float* gin_tmp  = alloc((size_t)NN * 64);
    float* gat_h    = alloc((size_t)NN * 128);
    float* gat_xl   = alloc((size_t)NN * 128);
    float* gat_xr   = alloc((size_t)NN * 128);
    float* gat_out  = alloc((size_t)NN * 64);
    float* pooled   = alloc((size_t)GG * 128);
    int* deg      = (int*)alloc((size_t)NN);
    int* fillc    = (int*)alloc((size_t)NN);
    int* excl     = (int*)alloc((size_t)NN);
    int* rowptr   = (int*)alloc((size_t)NN + 1);
    int* bsum     = (int*)alloc(256);
    int* boff     = (int*)alloc(256);
    int* gstart   = (int*)alloc((size_t)GG + 1);
    int* srcs_csr = (int*)alloc((size_t)EE);
    (void)ws_size; (void)n_in; (void)in_sizes; (void)out_size;

    const int TB = 256;
    const int NB_SCAN = cdiv(NN, 256);   // 196

    // =================== CSR build (shared by GIN + GAT) ===================
    k_filli<<<cdiv(NN, TB), TB, 0, stream>>>(deg, 0, NN);
    k_filli<<<cdiv(NN, TB), TB, 0, stream>>>(fillc, 0, NN);
    k_count<<<cdiv(EE, TB), TB, 0, stream>>>(dst, deg);
    k_scan1<<<NB_SCAN, 256, 0, stream>>>(deg, excl, bsum, NN);
    k_scan2<<<1, 256, 0, stream>>>(bsum, boff, NB_SCAN);
    k_scan3<<<cdiv(NN + 1, TB), TB, 0, stream>>>(excl, boff, rowptr);
    k_scatter_ids<<<cdiv(EE, TB), TB, 0, stream>>>(src, dst, rowptr, fillc, srcs_csr);
    k_gstart<<<1, 256, 0, stream>>>(batch, gstart);

    const int NR = cdiv(NN, 64);         // 782 row-blocks

    // =================== GIN encoder ===================
    const float* hin = x;
    for (int l = 0; l < 3; ++l) {
        k_gin_gather<<<cdiv((long)NN * 64, TB), TB, 0, stream>>>(hin, rowptr, srcs_csr, gin_hsum);
        k_mm<64, 64, true, true><<<dim3(NR, 1), 256, 0, stream>>>(
            gin_hsum, gin_w1 + l * 4096, gin_b1 + l * 64,
            gin_bn_g + l * 64, gin_bn_b + l * 64, gin_bn_m + l * 64, gin_bn_v + l * 64,
            gin_tmp, NN);
        k_mm<64, 64, false, true><<<dim3(NR, 1), 256, 0, stream>>>(
            gin_tmp, gin_w2 + l * 4096, gin_b2 + l * 64,
            nullptr, nullptr, nullptr, nullptr, gin_h, NN);
        hin = gin_h;
    }

    // =================== GATv2 encoder ===================
    const float* hg = x;
    for (int l = 0; l < 3; ++l) {
        if (l == 0) {
            k_mm<64, 128, false, false><<<dim3(NR, 2), 256, 0, stream>>>(
                hg, gat_wl[l], gat_bl[l], nullptr, nullptr, nullptr, nullptr, gat_xl, NN);
            k_mm<64, 128, false, false><<<dim3(NR, 2), 256, 0, stream>>>(
                hg, gat_wr[l], gat_br[l], nullptr, nullptr, nullptr, nullptr, gat_xr, NN);
            k_gat_fused<2, 128><<<NN, 128, 0, stream>>>(
                gat_xl, gat_xr, gat_att[l], rowptr, srcs_csr, gat_bias[l], gat_h);
            hg = gat_h;
        } else if (l == 1) {
            k_mm<128, 128, false, false><<<dim3(NR, 2), 256, 0, stream>>>(
                hg, gat_wl[l], gat_bl[l], nullptr, nullptr, nullptr, nullptr, gat_xl, NN);
            k_mm<128, 128, false, false><<<dim3(NR, 2), 256, 0, stream>>>(
                hg, gat_wr[l], gat_br[l], nullptr, nullptr, nullptr, nullptr, gat_xr, NN);
            k_gat_fused<2, 128><<<NN, 128, 0, stream>>>(
                gat_xl, gat_xr, gat_att[l], rowptr, srcs_csr, gat_bias[l], gat_h);
            hg = gat_h;
        } else {
            k_mm<128, 64, false, false><<<dim3(NR, 1), 256, 0, stream>>>(
                hg, gat_wl[l], gat_bl[l], nullptr, nullptr, nullptr, nullptr, gat_xl, NN);
            k_mm<128, 64, false, false><<<dim3(NR, 1), 256, 0, stream>>>(
                hg, gat_wr[l], gat_br[l], nullptr, nullptr, nullptr, nullptr, gat_xr, NN);
            k_gat_fused<1, 64><<<NN, 64, 0, stream>>>(
                gat_xl, gat_xr, gat_att[l], rowptr, srcs_csr, gat_bias[l], gat_out);
        }
    }

    // =================== pool + heads (segmented, zero atomics) ===================
    k_pool_seg<<<GG, 512, 0, stream>>>(gin_h, gat_out, gstart, pooled);
    k_head<<<GG, 64, 0, stream>>>(pooled, graph_w, graph_b, clf_w, clf_b, out);
}